// Round 4
// baseline (326.045 us; speedup 1.0000x reference)
//
#include <hip/hip_runtime.h>
#include <math.h>

// MMD loss, fp16 MFMA. N=M=4096, D=1024, sigma^2=2025.
// Round 14: T1 XCD SWIZZLE + RING-3 / 2 BLOCKS PER CU. R13 post-mortem:
// three schedules all pinned at ~95us / MfmaUtil 30% -> binder is memory
// LATENCY (staging served by L3/HBM: consecutive same-A-panel blocks
// round-robin across XCDs, L2 hit rate poor) plus 1 block/CU (96KB LDS)
// leaving barrier stalls uncovered. Fixes:
//  (a) bijective XCD swizzle w=(bid&7)*132+(bid>>3) (1056=8*132): each XCD
//      gets a contiguous triangular run -> A/B panel reuse lands in its L2.
//  (b) ring-3 LDS (72.1 KB) -> 2 blocks/CU (4 waves/SIMD): sibling block
//      fills residual vmcnt/barrier stalls (m114 mechanism).
// Phase: BAR; STAGE(p+2); DSREAD(p+1); MFMA(p); VMCNT0. Stage-after-barrier
// makes ring-3 race-free: slot (p+2)%3==(p-1)%3 readers (DSREAD in p-2,
// lgkm-retired before MFMA(p-1)) completed before any wave passed BAR(p).
// Per-wave vmcnt(0) before the next BAR preserves the glds publish
// invariant. 6-phase unroll keeps ring slots and fragment sets literal.
// Packed K-major panels, 2-bit XOR swizzle (0 conflicts), triangular
// 256x128 grid, fp64 partials -- unchanged from R12/R13.

typedef _Float16 f16_t;
typedef _Float16 f16x4 __attribute__((ext_vector_type(4)));
typedef _Float16 f16x8 __attribute__((ext_vector_type(8)));
typedef float floatx4 __attribute__((ext_vector_type(4)));

#define NROWS 4096
#define MROWS 4096
#define DDIM  1024
#define BM    256                   // A rows per block
#define BN    128                   // B rows per block
#define BK    32                    // fp16 elements per K-tile (64 B/row)
#define NKT   (DDIM / BK)           // 32 K-tiles
#define PSTRIDE (4096 * BK)         // f16 elems per packed K-panel (131072)
#define NTR   (NROWS / BM)          // 16 row tiles
#define NTC   (NROWS / BN)          // 32 col tiles
#define XXB   272                   // sum_{i=0..15} (32-2i) triangular tiles
#define NBLK  (2 * XXB + NTR * NTC) // 1056 blocks = 8 * 132

// ---------------------------------------------------------------- convert
// Wave-per-row; fully coalesced float4 loads. Stores go to the PACKED layout
// Xp[kt][row][32]: lane l, iter c covers k = c*256 + l*4 -> panel c*8+(l>>3),
// pos (l&7)*4. Norm of the ROUNDED row shuffle-reduced in-wave.
__global__ __launch_bounds__(256) void convert_kernel(
    const float* __restrict__ X, const float* __restrict__ Y,
    f16_t* __restrict__ Xp, f16_t* __restrict__ Yp,
    float* __restrict__ nx, float* __restrict__ ny) {
    const int wid  = threadIdx.x >> 6;
    const int lane = threadIdx.x & 63;
    const int row  = blockIdx.x * 4 + wid;        // 0..8191
    const float* src;
    f16_t* dstp;
    float* nrm;
    int r;
    if (row < NROWS) {
        r = row;         src = X + (size_t)r * DDIM;
        dstp = Xp;  nrm = nx;
    } else {
        r = row - NROWS; src = Y + (size_t)r * DDIM;
        dstp = Yp;  nrm = ny;
    }
    const float4* s4 = (const float4*)src;        // 256 float4 per row
    float s = 0.f;
    #pragma unroll
    for (int c = 0; c < 4; c++) {
        float4 v = s4[c * 64 + lane];
        f16x4 h;
        h[0] = (f16_t)v.x; h[1] = (f16_t)v.y;
        h[2] = (f16_t)v.z; h[3] = (f16_t)v.w;
        // k = c*256 + lane*4 -> kt = c*8 + (lane>>3), pos = (lane&7)*4
        *(f16x4*)(dstp + (size_t)(c * 8 + (lane >> 3)) * PSTRIDE
                       + (size_t)r * BK + (lane & 7) * 4) = h;
        float h0 = (float)h[0], h1 = (float)h[1];
        float h2 = (float)h[2], h3 = (float)h[3];
        s += h0 * h0 + h1 * h1 + h2 * h2 + h3 * h3;
    }
    #pragma unroll
    for (int off = 32; off > 0; off >>= 1) s += __shfl_down(s, off);
    if (lane == 0) nrm[r] = s;
}

// ---------------------------------------------------------------- main GEMM
// Stage tile tt_ into ring slot slot_ (literal). Packed layout: each instr
// reads 1KB CONTIGUOUS.
#define STAGE(tt_, slot_) do {                                                 \
    const size_t kk_ = (size_t)(tt_) * PSTRIDE;                                \
    __builtin_amdgcn_global_load_lds(                                          \
        (const __attribute__((address_space(1))) void*)(gA + kk_),             \
        (__attribute__((address_space(3))) void*)(&ldsA[slot_][wave * 1024]),  \
        16, 0, 0);                                                             \
    __builtin_amdgcn_global_load_lds(                                          \
        (const __attribute__((address_space(1))) void*)(gA + kk_ + 16 * BK),   \
        (__attribute__((address_space(3))) void*)(&ldsA[slot_][wave * 1024 + 512]), \
        16, 0, 0);                                                             \
    __builtin_amdgcn_global_load_lds(                                          \
        (const __attribute__((address_space(1))) void*)(gB + kk_),             \
        (__attribute__((address_space(3))) void*)(&ldsB[slot_][wave * 512]),   \
        16, 0, 0);                                                             \
  } while (0)

#define VMCNT0 asm volatile("s_waitcnt vmcnt(0)" ::: "memory")
#define BAR    __builtin_amdgcn_s_barrier()

#define DSREAD(slot_, AH_, BH_) do {                                           \
    _Pragma("unroll")                                                          \
    for (int s_ = 0; s_ < 4; s_++) {                                           \
        AH_[s_] = *(const f16x8*)&ldsA[slot_][aoff + s_ * 16 * BK];            \
        BH_[s_] = *(const f16x8*)&ldsB[slot_][boff + s_ * 16 * BK];            \
    }                                                                          \
  } while (0)

#define MFMA16(AH_, BH_) do {                                                  \
    __builtin_amdgcn_s_setprio(1);                                             \
    _Pragma("unroll")                                                          \
    for (int i_ = 0; i_ < 4; i_++)                                             \
        _Pragma("unroll")                                                      \
        for (int j_ = 0; j_ < 4; j_++)                                         \
            acc[i_][j_] = __builtin_amdgcn_mfma_f32_16x16x32_f16(              \
                AH_[i_], BH_[j_], acc[i_][j_], 0, 0, 0);                       \
    __builtin_amdgcn_s_setprio(0);                                             \
  } while (0)

// Phase p: BAR; STAGE(p+2 -> sslot); DSREAD(p+1 -> rslot, other set);
// MFMA(p, current set); VMCNT0 (drain own stage before next BAR).
#define PHASE(st_, ss_, rs_, AHR_, BHR_, AHC_, BHC_) do {                      \
    BAR;                                                                       \
    STAGE(st_, ss_);                                                           \
    DSREAD(rs_, AHR_, BHR_);                                                   \
    MFMA16(AHC_, BHC_);                                                        \
    VMCNT0;                                                                    \
  } while (0)

__global__ __launch_bounds__(512, 4) void mmd_mfma(
    const f16_t* __restrict__ Xp, const f16_t* __restrict__ Yp,
    const float* __restrict__ nx, const float* __restrict__ ny,
    double* __restrict__ partials) {
    // Ring-3 buffer: 3 x (A 256x32 + B 128x32) fp16 = 72 KB -> 2 blocks/CU.
    // Row r of a tile stores logical chunk c (16 B) at phys chunk c ^ f(r),
    // f(r) = ((r&15)>>1)&3 (verified 0-conflict rounds 11-13).
    __shared__ __align__(16) f16_t ldsA[3][BM * BK];   // 3 x 16 KB
    __shared__ __align__(16) f16_t ldsB[3][BN * BK];   // 3 x  8 KB
    __shared__ double wred[8];

    // T1: bijective XCD swizzle. HW round-robins blockIdx across 8 XCDs;
    // remap so each XCD executes a CONTIGUOUS run of the triangular
    // enumeration (A/B panel reuse -> its private L2). 1056 = 8 * 132.
    const int b = ((blockIdx.x & 7) * (NBLK / 8)) + (blockIdx.x >> 3);

    const f16_t *Abase, *Bbase;
    const float *nAp, *nBp;
    int arow0, brow0;                 // panel row offsets of the tiles
    double coef;
    if (b < 2 * XXB) {
        int u = (b < XXB) ? b : b - XXB;
        int i = 0;
        while (u >= NTC - 2 * i) { u -= NTC - 2 * i; i++; }
        const int ti = i, tj = 2 * i + u;         // tj in [2i, 32)
        const double w = (tj >= 2 * i + 2) ? 2.0 : 1.0;  // straddle tiles w=1
        const f16_t* base;
        const float* nb_;
        double denom;
        if (b < XXB) { base = Xp; nb_ = nx; denom = (double)NROWS * (double)(NROWS - 1); }
        else         { base = Yp; nb_ = ny; denom = (double)MROWS * (double)(MROWS - 1); }
        Abase = base; Bbase = base;
        arow0 = ti * BM;  brow0 = tj * BN;
        nAp = nb_ + ti * BM;  nBp = nb_ + tj * BN;
        coef = w / denom;
    } else {
        const int u = b - 2 * XXB;
        const int ti = u >> 5, tj = u & 31;
        Abase = Xp; Bbase = Yp;
        arow0 = ti * BM;  brow0 = tj * BN;
        nAp = nx + ti * BM;  nBp = ny + tj * BN;
        coef = -2.0 / ((double)NROWS * (double)MROWS);
    }

    const int tid  = threadIdx.x;
    const int wave = tid >> 6;          // 0..7
    const int lane = tid & 63;
    const int wm   = wave >> 1;         // 0..3 : 4 M-waves x 64 rows
    const int wn   = wave & 1;          // 0..1 : 2 N-waves x 64 cols
    const int m    = lane & 15;
    const int quad = lane >> 4;
    // read-side swizzled chunk offset (f16 units): phys = quad ^ ((row>>1)&3)
    const int sw8  = (quad ^ ((m >> 1) & 3)) * 8;
    const int aoff = (wm * 64 + m) * BK + sw8;      // + s*512 per 16-row frag
    const int boff = (wn * 64 + m) * BK + sw8;

    // staging: per K-tile, wave w covers A rows [w*32, w*32+32) (2 instrs) and
    // B rows [w*16, w*16+16) (1 instr). glds writes linearly: lane l -> row
    // base+(l>>2), phys chunk l&3; fetch the inverse-swizzled global chunk
    // (l&3)^((l>>3)&3) so phys chunk p of row r holds logical p^((r>>1)&3).
    const int lr = lane >> 2;
    const int lc = (lane & 3) ^ ((lane >> 3) & 3);
    const f16_t* gA = Abase + (size_t)(arow0 + wave * 32 + lr) * BK + lc * 8;
    const f16_t* gB = Bbase + (size_t)(brow0 + wave * 16 + lr) * BK + lc * 8;

    floatx4 acc[4][4];
    #pragma unroll
    for (int i = 0; i < 4; i++)
        #pragma unroll
        for (int j = 0; j < 4; j++) acc[i][j] = (floatx4){0.f, 0.f, 0.f, 0.f};

    f16x8 ahA[4], bhA[4], ahB[4], bhB[4];

    // prologue: stage tiles 0,1; drain own loads; publish; read tile 0.
    STAGE(0, 0); STAGE(1, 1);
    VMCNT0;
    BAR;
    DSREAD(0, ahA, bhA);

    // steady state: phases 0..29, 6-phase unroll (ring slots + sets literal).
    // Slot pattern (p mod 6): stage (p+2)%3 = 2,0,1,2,0,1; read (p+1)%3 =
    // 1,2,0,1,2,0; compute set alternates A,B,A,B,A,B.
    for (int tt = 0; tt < NKT - 2; tt += 6) {
        PHASE(tt + 2, 2, 1, ahB, bhB, ahA, bhA);   // p = tt+0
        PHASE(tt + 3, 0, 2, ahA, bhA, ahB, bhB);   // p = tt+1
        PHASE(tt + 4, 1, 0, ahB, bhB, ahA, bhA);   // p = tt+2
        PHASE(tt + 5, 2, 1, ahA, bhA, ahB, bhB);   // p = tt+3
        PHASE(tt + 6, 0, 2, ahB, bhB, ahA, bhA);   // p = tt+4
        PHASE(tt + 7, 1, 0, ahA, bhA, ahB, bhB);   // p = tt+5
    }
    // tail: phase 30 (read tile 31 from slot 1, no stage), phase 31.
    BAR;
    DSREAD(1, ahB, bhB);
    MFMA16(ahA, bhA);
    MFMA16(ahB, bhB);

    // epilogue: C/D layout col=lane&15 (B-row), row=quad*4+reg (A-row).
    const float inv_s2 = 1.0f / 2025.0f;
    float nbv[4];
    #pragma unroll
    for (int j = 0; j < 4; j++) nbv[j] = nBp[wn * 64 + j * 16 + m];
    float lsum = 0.f;
    #pragma unroll
    for (int i = 0; i < 4; i++) {
        floatx4 na4 = *(const floatx4*)&nAp[wm * 64 + i * 16 + quad * 4];
        #pragma unroll
        for (int j = 0; j < 4; j++)
            #pragma unroll
            for (int r = 0; r < 4; r++) {
                float arg = (2.f * acc[i][j][r] - na4[r] - nbv[j]) * inv_s2;
                lsum += __expf(arg);
            }
    }

    // in-wave fp64 reduce, 8-wave LDS combine; plain store (no fences).
    double d = (double)lsum;
    #pragma unroll
    for (int off = 32; off > 0; off >>= 1) d += __shfl_down(d, off);
    if (lane == 0) wred[wave] = d;
    __syncthreads();
    if (tid == 0) {
        double s = 0.0;
        #pragma unroll
        for (int w = 0; w < 8; w++) s += wred[w];
        partials[b] = s * coef;
    }
}

__global__ __launch_bounds__(256) void final_reduce(const double* __restrict__ partials,
                                                    float* __restrict__ out) {
    __shared__ double red[256];
    int t = threadIdx.x;
    double s = 0.0;
    for (int i = t; i < NBLK; i += 256) s += partials[i];
    red[t] = s;
    __syncthreads();
    for (int off = 128; off > 0; off >>= 1) {
        if (t < off) red[t] += red[t + off];
        __syncthreads();
    }
    if (t == 0) {
        // analytic diagonal subtraction: 1/(n-1) + 1/(m-1)
        double mmd = red[0] - 1.0 / (double)(NROWS - 1) - 1.0 / (double)(MROWS - 1);
        out[0] = (float)mmd;
    }
}

extern "C" void kernel_launch(void* const* d_in, const int* in_sizes, int n_in,
                              void* d_out, int out_size, void* d_ws, size_t ws_size,
                              hipStream_t stream) {
    const float* X = (const float*)d_in[0];   // inputs  [4096,1024] fp32
    const float* Y = (const float*)d_in[1];   // samples [4096,1024] fp32
    float* out = (float*)d_out;

    // workspace: partials | nx | ny | Xp | Yp  (~16.7 MB)
    char* p = (char*)d_ws;
    double* partials = (double*)p;            p += ((size_t)NBLK * sizeof(double) + 255) & ~255ULL;
    float* nx = (float*)p;                    p += (size_t)NROWS * sizeof(float);
    float* ny = (float*)p;                    p += (size_t)MROWS * sizeof(float);
    f16_t* Xp = (f16_t*)p;                    p += (size_t)NROWS * DDIM * sizeof(f16_t);
    f16_t* Yp = (f16_t*)p;

    convert_kernel<<<(NROWS + MROWS) / 4, 256, 0, stream>>>(X, Y, Xp, Yp, nx, ny);
    mmd_mfma<<<NBLK, 512, 0, stream>>>(Xp, Yp, nx, ny, partials);
    final_reduce<<<1, 256, 0, stream>>>(partials, out);
}

// Round 5
// 186.067 us; speedup vs baseline: 1.7523x; 1.7523x over previous
//
#include <hip/hip_runtime.h>
#include <math.h>

// MMD loss, fp16 MFMA. N=M=4096, D=1024, sigma^2=2025.
// Round 15: B DIRECT-TO-REGISTER (LDS diet). R4 post-mortem: launch_bounds
// (512,4) capped regs at 128/wave -> 64-VGPR alloc + 558MB scratch spill;
// reverted to (512,2). R0/R2/R3 all tie at ~95us / MfmaUtil 30% because the
// invariant is LDS service (~88KB/block-phase ~= 1035cy) > MFMA (620cy) --
// the LDS pipe is the pole, not the schedule. Fix: B fragments load straight
// from the packed K-major panels into registers (per instr: 16 rows x 64B =
// 1KB contiguous, same bytes the LDS path produced, no swizzle); B
// double-buffers in regs. LDS now A-only ring-4 (64KB), content/phase 48KB
// (~565cy) < MFMA 620cy -> MFMA-pole. Cost: 4x B redundancy on L2 (~32KB/
// phase/block) -- mitigated by T1 bijective XCD swizzle (kept from R4).
// vmcnt protocol: 6 VMEM/phase (2 glds A + 4 B-loads) -> vmcnt(6) counted;
// phase = {STAGE_A(p+2); BLOAD(p+1); vmcnt(6); BAR; DSREAD_A(p+1); MFMA(p)}.
// Ring-4 race-free: STAGE(p+2) hits slot (p-2)&3 whose reads retired before
// MFMA(p-2), which precedes BAR(p-1) in program order of every wave.
// Packed panels, 2-bit XOR swizzle on A (0 conflicts), triangular 256x128
// grid (1056 blocks = 8*132), fp64 partials -- unchanged.

typedef _Float16 f16_t;
typedef _Float16 f16x4 __attribute__((ext_vector_type(4)));
typedef _Float16 f16x8 __attribute__((ext_vector_type(8)));
typedef float floatx4 __attribute__((ext_vector_type(4)));

#define NROWS 4096
#define MROWS 4096
#define DDIM  1024
#define BM    256                   // A rows per block
#define BN    128                   // B rows per block
#define BK    32                    // fp16 elements per K-tile (64 B/row)
#define NKT   (DDIM / BK)           // 32 K-tiles
#define PSTRIDE (4096 * BK)         // f16 elems per packed K-panel (131072)
#define NTR   (NROWS / BM)          // 16 row tiles
#define NTC   (NROWS / BN)          // 32 col tiles
#define XXB   272                   // sum_{i=0..15} (32-2i) triangular tiles
#define NBLK  (2 * XXB + NTR * NTC) // 1056 blocks = 8 * 132

// ---------------------------------------------------------------- convert
// Wave-per-row; fully coalesced float4 loads. Stores go to the PACKED layout
// Xp[kt][row][32]: lane l, iter c covers k = c*256 + l*4 -> panel c*8+(l>>3),
// pos (l&7)*4. Norm of the ROUNDED row shuffle-reduced in-wave.
__global__ __launch_bounds__(256) void convert_kernel(
    const float* __restrict__ X, const float* __restrict__ Y,
    f16_t* __restrict__ Xp, f16_t* __restrict__ Yp,
    float* __restrict__ nx, float* __restrict__ ny) {
    const int wid  = threadIdx.x >> 6;
    const int lane = threadIdx.x & 63;
    const int row  = blockIdx.x * 4 + wid;        // 0..8191
    const float* src;
    f16_t* dstp;
    float* nrm;
    int r;
    if (row < NROWS) {
        r = row;         src = X + (size_t)r * DDIM;
        dstp = Xp;  nrm = nx;
    } else {
        r = row - NROWS; src = Y + (size_t)r * DDIM;
        dstp = Yp;  nrm = ny;
    }
    const float4* s4 = (const float4*)src;        // 256 float4 per row
    float s = 0.f;
    #pragma unroll
    for (int c = 0; c < 4; c++) {
        float4 v = s4[c * 64 + lane];
        f16x4 h;
        h[0] = (f16_t)v.x; h[1] = (f16_t)v.y;
        h[2] = (f16_t)v.z; h[3] = (f16_t)v.w;
        // k = c*256 + lane*4 -> kt = c*8 + (lane>>3), pos = (lane&7)*4
        *(f16x4*)(dstp + (size_t)(c * 8 + (lane >> 3)) * PSTRIDE
                       + (size_t)r * BK + (lane & 7) * 4) = h;
        float h0 = (float)h[0], h1 = (float)h[1];
        float h2 = (float)h[2], h3 = (float)h[3];
        s += h0 * h0 + h1 * h1 + h2 * h2 + h3 * h3;
    }
    #pragma unroll
    for (int off = 32; off > 0; off >>= 1) s += __shfl_down(s, off);
    if (lane == 0) nrm[r] = s;
}

// ---------------------------------------------------------------- main GEMM
// Stage A-tile tt_ into ring slot slot_ (literal). 2 glds instrs per wave,
// each 1KB contiguous (packed layout).
#define STAGEA(tt_, slot_) do {                                                \
    const size_t kk_ = (size_t)(tt_) * PSTRIDE;                                \
    __builtin_amdgcn_global_load_lds(                                          \
        (const __attribute__((address_space(1))) void*)(gA + kk_),             \
        (__attribute__((address_space(3))) void*)(&ldsA[slot_][wave * 1024]),  \
        16, 0, 0);                                                             \
    __builtin_amdgcn_global_load_lds(                                          \
        (const __attribute__((address_space(1))) void*)(gA + kk_ + 16 * BK),   \
        (__attribute__((address_space(3))) void*)(&ldsA[slot_][wave * 1024 + 512]), \
        16, 0, 0);                                                             \
  } while (0)

// Load B fragments of tile tt_ straight from the packed panel into regs.
// Lane reads row (wn*64 + s*16 + m), bytes quad*16..: per s the wave covers
// 16 rows x 64B = 1KB contiguous. Same bytes the old LDS path delivered.
#define BLOAD(tt_, BH_) do {                                                   \
    const size_t kk_ = (size_t)(tt_) * PSTRIDE;                                \
    _Pragma("unroll")                                                          \
    for (int s_ = 0; s_ < 4; s_++)                                             \
        BH_[s_] = *(const f16x8*)(gBfrag + kk_ + s_ * 16 * BK);                \
  } while (0)

#define VM6   asm volatile("s_waitcnt vmcnt(6)" ::: "memory")
#define VM4   asm volatile("s_waitcnt vmcnt(4)" ::: "memory")
#define VM0   asm volatile("s_waitcnt vmcnt(0)" ::: "memory")
#define BAR   __builtin_amdgcn_s_barrier()

#define DSREADA(slot_, AH_) do {                                               \
    _Pragma("unroll")                                                          \
    for (int s_ = 0; s_ < 4; s_++)                                             \
        AH_[s_] = *(const f16x8*)&ldsA[slot_][aoff + s_ * 16 * BK];            \
  } while (0)

#define MFMA16(AH_, BH_) do {                                                  \
    __builtin_amdgcn_s_setprio(1);                                             \
    _Pragma("unroll")                                                          \
    for (int i_ = 0; i_ < 4; i_++)                                             \
        _Pragma("unroll")                                                      \
        for (int j_ = 0; j_ < 4; j_++)                                         \
            acc[i_][j_] = __builtin_amdgcn_mfma_f32_16x16x32_f16(              \
                AH_[i_], BH_[j_], acc[i_][j_], 0, 0, 0);                       \
    __builtin_amdgcn_s_setprio(0);                                             \
  } while (0)

// Phase p: stage A(p+2); load B(p+1) regs; vmcnt(6) [A(p+1) landed, B(p)
// ready]; barrier [publish A(p+1)]; ds_read A(p+1); MFMA(p).
#define PH(st_, ss_, rs_, AHR_, BHR_, AHC_, BHC_) do {                         \
    STAGEA(st_, ss_);                                                          \
    BLOAD((st_) - 1, BHR_);                                                    \
    VM6;                                                                       \
    BAR;                                                                       \
    DSREADA(rs_, AHR_);                                                        \
    MFMA16(AHC_, BHC_);                                                        \
  } while (0)

__global__ __launch_bounds__(512, 2) void mmd_mfma(
    const f16_t* __restrict__ Xp, const f16_t* __restrict__ Yp,
    const float* __restrict__ nx, const float* __restrict__ ny,
    double* __restrict__ partials) {
    // Ring-4 A-only buffer: 4 x 256x32 fp16 = 64 KB.
    // Row r stores logical chunk c (16B) at phys chunk c ^ (((r&15)>>1)&3)
    // (verified 0-conflict rounds 11-13).
    __shared__ __align__(16) f16_t ldsA[4][BM * BK];   // 4 x 16 KB
    __shared__ double wred[8];

    // T1: bijective XCD swizzle (1056 = 8*132). HW round-robins blockIdx
    // across XCDs; remap so each XCD runs a contiguous triangular range ->
    // A-panel + B-panel reuse lands in its private L2 (B is read 4x/block
    // now, so this matters more than ever).
    const int b = ((blockIdx.x & 7) * (NBLK / 8)) + (blockIdx.x >> 3);

    const f16_t *Abase, *Bbase;
    const float *nAp, *nBp;
    int arow0, brow0;                 // panel row offsets of the tiles
    double coef;
    if (b < 2 * XXB) {
        int u = (b < XXB) ? b : b - XXB;
        int i = 0;
        while (u >= NTC - 2 * i) { u -= NTC - 2 * i; i++; }
        const int ti = i, tj = 2 * i + u;         // tj in [2i, 32)
        const double w = (tj >= 2 * i + 2) ? 2.0 : 1.0;  // straddle tiles w=1
        const f16_t* base;
        const float* nb_;
        double denom;
        if (b < XXB) { base = Xp; nb_ = nx; denom = (double)NROWS * (double)(NROWS - 1); }
        else         { base = Yp; nb_ = ny; denom = (double)MROWS * (double)(MROWS - 1); }
        Abase = base; Bbase = base;
        arow0 = ti * BM;  brow0 = tj * BN;
        nAp = nb_ + ti * BM;  nBp = nb_ + tj * BN;
        coef = w / denom;
    } else {
        const int u = b - 2 * XXB;
        const int ti = u >> 5, tj = u & 31;
        Abase = Xp; Bbase = Yp;
        arow0 = ti * BM;  brow0 = tj * BN;
        nAp = nx + ti * BM;  nBp = ny + tj * BN;
        coef = -2.0 / ((double)NROWS * (double)MROWS);
    }

    const int tid  = threadIdx.x;
    const int wave = tid >> 6;          // 0..7
    const int lane = tid & 63;
    const int wm   = wave >> 1;         // 0..3 : 4 M-waves x 64 rows
    const int wn   = wave & 1;          // 0..1 : 2 N-waves x 64 cols
    const int m    = lane & 15;
    const int quad = lane >> 4;
    // A read-side swizzled chunk offset: phys = quad ^ ((row>>1)&3)
    const int sw8  = (quad ^ ((m >> 1) & 3)) * 8;
    const int aoff = (wm * 64 + m) * BK + sw8;      // + s*512 per 16-row frag

    // A staging: wave w covers rows [w*32, w*32+32) (2 instrs). glds writes
    // linearly: lane l -> row base+(l>>2), phys chunk l&3; fetch global
    // chunk (l&3)^((l>>3)&3) so phys chunk p of row r holds logical
    // p^((r>>1)&3).
    const int lr = lane >> 2;
    const int lc = (lane & 3) ^ ((lane >> 3) & 3);
    const f16_t* gA = Abase + (size_t)(arow0 + wave * 32 + lr) * BK + lc * 8;
    // B fragment pointer: row (brow0 + wn*64 + m), k-chunk quad (16B).
    const f16_t* gBfrag = Bbase + (size_t)(brow0 + wn * 64 + m) * BK + quad * 8;

    floatx4 acc[4][4];
    #pragma unroll
    for (int i = 0; i < 4; i++)
        #pragma unroll
        for (int j = 0; j < 4; j++) acc[i][j] = (floatx4){0.f, 0.f, 0.f, 0.f};

    f16x8 ahA[4], ahB[4], bhA[4], bhB[4];

    // prologue: stage A0,A1; load B0; vmcnt(6) [newest 6 = A1+B0 -> A0
    // landed]; publish; read A0.
    STAGEA(0, 0); STAGEA(1, 1);
    BLOAD(0, bhA);
    VM6;
    BAR;
    DSREADA(0, ahA);

    // steady state: phases 0..27 (4-phase unroll; ring slots + sets literal).
    // Tile k lives in slot k&3; fragment sets alternate with tile parity
    // (even tile -> set A).
    for (int tt = 0; tt < NKT - 4; tt += 4) {
        PH(tt + 2, 2, 1, ahB, bhB, ahA, bhA);   // p = tt+0
        PH(tt + 3, 3, 2, ahA, bhA, ahB, bhB);   // p = tt+1
        PH(tt + 4, 0, 3, ahB, bhB, ahA, bhA);   // p = tt+2
        PH(tt + 5, 1, 0, ahA, bhA, ahB, bhB);   // p = tt+3
    }
    // tail: p = 28..31
    PH(30, 2, 1, ahB, bhB, ahA, bhA);           // p = 28
    PH(31, 3, 2, ahA, bhA, ahB, bhB);           // p = 29
    BLOAD(31, bhB);                              // p = 30
    VM4;                                         //   newest 4 = B31 -> A31,B30 done
    BAR;                                         //   publish A31
    DSREADA(3, ahB);
    MFMA16(ahA, bhA);
    VM0;                                         // p = 31: B31 ready
    MFMA16(ahB, bhB);

    // epilogue: C/D layout col=lane&15 (B-row), row=quad*4+reg (A-row).
    const float inv_s2 = 1.0f / 2025.0f;
    float nbv[4];
    #pragma unroll
    for (int j = 0; j < 4; j++) nbv[j] = nBp[wn * 64 + j * 16 + m];
    float lsum = 0.f;
    #pragma unroll
    for (int i = 0; i < 4; i++) {
        floatx4 na4 = *(const floatx4*)&nAp[wm * 64 + i * 16 + quad * 4];
        #pragma unroll
        for (int j = 0; j < 4; j++)
            #pragma unroll
            for (int r = 0; r < 4; r++) {
                float arg = (2.f * acc[i][j][r] - na4[r] - nbv[j]) * inv_s2;
                lsum += __expf(arg);
            }
    }

    // in-wave fp64 reduce, 8-wave LDS combine; plain store (no fences).
    double d = (double)lsum;
    #pragma unroll
    for (int off = 32; off > 0; off >>= 1) d += __shfl_down(d, off);
    if (lane == 0) wred[wave] = d;
    __syncthreads();
    if (tid == 0) {
        double s = 0.0;
        #pragma unroll
        for (int w = 0; w < 8; w++) s += wred[w];
        partials[b] = s * coef;
    }
}

__global__ __launch_bounds__(256) void final_reduce(const double* __restrict__ partials,
                                                    float* __restrict__ out) {
    __shared__ double red[256];
    int t = threadIdx.x;
    double s = 0.0;
    for (int i = t; i < NBLK; i += 256) s += partials[i];
    red[t] = s;
    __syncthreads();
    for (int off = 128; off > 0; off >>= 1) {
        if (t < off) red[t] += red[t + off];
        __syncthreads();
    }
    if (t == 0) {
        // analytic diagonal subtraction: 1/(n-1) + 1/(m-1)
        double mmd = red[0] - 1.0 / (double)(NROWS - 1) - 1.0 / (double)(MROWS - 1);
        out[0] = (float)mmd;
    }
}

extern "C" void kernel_launch(void* const* d_in, const int* in_sizes, int n_in,
                              void* d_out, int out_size, void* d_ws, size_t ws_size,
                              hipStream_t stream) {
    const float* X = (const float*)d_in[0];   // inputs  [4096,1024] fp32
    const float* Y = (const float*)d_in[1];   // samples [4096,1024] fp32
    float* out = (float*)d_out;

    // workspace: partials | nx | ny | Xp | Yp  (~16.7 MB)
    char* p = (char*)d_ws;
    double* partials = (double*)p;            p += ((size_t)NBLK * sizeof(double) + 255) & ~255ULL;
    float* nx = (float*)p;                    p += (size_t)NROWS * sizeof(float);
    float* ny = (float*)p;                    p += (size_t)MROWS * sizeof(float);
    f16_t* Xp = (f16_t*)p;                    p += (size_t)NROWS * DDIM * sizeof(f16_t);
    f16_t* Yp = (f16_t*)p;

    convert_kernel<<<(NROWS + MROWS) / 4, 256, 0, stream>>>(X, Y, Xp, Yp, nx, ny);
    mmd_mfma<<<NBLK, 512, 0, stream>>>(Xp, Yp, nx, ny, partials);
    final_reduce<<<1, 256, 0, stream>>>(partials, out);
}

// Round 6
// 180.125 us; speedup vs baseline: 1.8101x; 1.0330x over previous
//
#include <hip/hip_runtime.h>
#include <math.h>

// MMD loss, fp16 MFMA. N=M=4096, D=1024, sigma^2=2025.
// Round 16: CONSOLIDATION ON R0. Evidence r10-r15: R0's simple 128x128 /
// 4-wave / drain-loop structure with multi-block-per-CU TLP (97.6us) ties or
// beats every 1-block/CU fancy schedule (8-phase counted vmcnt, register
// pipeline, B-to-regs: 112/94.5/117.8us). The binder is exposed memory
// latency; co-resident blocks cover it (m114), barriers don't. So: keep R0's
// kernel body EXACTLY (LDS chunk swizzle verified 0-conflict, 2-barrier
// drain loop, hoisted norms, fp64 partials) and add only proven orthogonal
// levers it never had:
//  (a) K-major packed panels Xp/Yp[kt][row][32] (R2's isolated win): every
//      global_load_lds reads 1KB CONTIGUOUS instead of 16 x 64B at 2KB
//      stride -- the fine-grained-request stall R2 removed.
//  (b) T1 bijective XCD swizzle (2080 = 8*260): each XCD runs a contiguous
//      triangular range -> A/B panel reuse lands in its private L2.
//  (c) final_reduce fused via fp64 device atomics + last-block-writes-out
//      (convert block 0 zero-inits; per-block atomic order enforced by
//      vmcnt(0) between sum-add and cnt-add). One launch saved.

typedef _Float16 f16_t;
typedef _Float16 f16x4 __attribute__((ext_vector_type(4)));
typedef _Float16 f16x8 __attribute__((ext_vector_type(8)));
typedef float floatx4 __attribute__((ext_vector_type(4)));

#define NROWS 4096
#define MROWS 4096
#define DDIM  1024
#define BM    128
#define BK    32                      // fp16 elements per K-step (64 B/row)
#define TILE  (BM * BK)               // 4096 f16 per tile (8 KB)
#define NKT   (DDIM / BK)             // 32 K-steps
#define PSTRIDE (4096 * BK)           // f16 elems per packed K-panel (256 KB)
#define NT    (NROWS / BM)            // 32 tiles per dim
#define TRI   (NT * (NT + 1) / 2)     // 528 triangular tiles
#define NBLK  (2 * TRI + NT * NT)     // 2080 blocks = 8 * 260

// ---------------------------------------------------------------- convert
// Wave-per-row: 2048 blocks x 4 waves cover 8192 rows. Each lane loads
// 4 float4 (fully coalesced), converts to fp16, stores to the PACKED layout
// Xp[kt][row][32]: lane l, iter c covers k = c*256+l*4 -> panel c*8+(l>>3),
// pos (l&7)*4. Norm of the ROUNDED row shuffle-reduced in-wave.
// Block 0 thread 0 also zero-inits the fused-reduce accumulators (visible
// to mmd_mfma via end-of-kernel flush + stream order).
__global__ __launch_bounds__(256) void convert_kernel(
    const float* __restrict__ X, const float* __restrict__ Y,
    f16_t* __restrict__ Xp, f16_t* __restrict__ Yp,
    float* __restrict__ nx, float* __restrict__ ny,
    double* __restrict__ gsum, int* __restrict__ gcnt) {
    if (blockIdx.x == 0 && threadIdx.x == 0) { *gsum = 0.0; *gcnt = 0; }
    const int wid  = threadIdx.x >> 6;
    const int lane = threadIdx.x & 63;
    const int row  = blockIdx.x * 4 + wid;        // 0..8191
    const float* src;
    f16_t* dstp;
    float* nrm;
    int r;
    if (row < NROWS) {
        r = row;         src = X + (size_t)r * DDIM;
        dstp = Xp;  nrm = nx;
    } else {
        r = row - NROWS; src = Y + (size_t)r * DDIM;
        dstp = Yp;  nrm = ny;
    }
    const float4* s4 = (const float4*)src;        // 256 float4 per row
    float s = 0.f;
    #pragma unroll
    for (int c = 0; c < 4; c++) {
        float4 v = s4[c * 64 + lane];
        f16x4 h;
        h[0] = (f16_t)v.x; h[1] = (f16_t)v.y;
        h[2] = (f16_t)v.z; h[3] = (f16_t)v.w;
        // k = c*256 + lane*4 -> kt = c*8 + (lane>>3), pos = (lane&7)*4
        *(f16x4*)(dstp + (size_t)(c * 8 + (lane >> 3)) * PSTRIDE
                       + (size_t)r * BK + (lane & 7) * 4) = h;
        float h0 = (float)h[0], h1 = (float)h[1];
        float h2 = (float)h[2], h3 = (float)h[3];
        s += h0 * h0 + h1 * h1 + h2 * h2 + h3 * h3;
    }
    #pragma unroll
    for (int off = 32; off > 0; off >>= 1) s += __shfl_down(s, off);
    if (lane == 0) nrm[r] = s;
}

// ---------------------------------------------------------------- main GEMM
__global__ __launch_bounds__(256) void mmd_mfma(
    const f16_t* __restrict__ Xp, const f16_t* __restrict__ Yp,
    const float* __restrict__ nx, const float* __restrict__ ny,
    double* __restrict__ gsum, int* __restrict__ gcnt,
    float* __restrict__ out) {
    // A-tile | B-tile, each BM x BK fp16 = 8 KB (16 KB total). Row stride
    // BK (64 B); slot chunk c' of row r holds global chunk c'^f(r),
    // f(r) = (r^(r>>2))&3 (verified 0-conflict, previous session).
    __shared__ __align__(16) f16_t lds[2 * TILE];
    __shared__ double wred[4];

    // T1: bijective XCD swizzle (2080 = 8*260). HW round-robins blockIdx
    // across 8 XCDs; remap so each XCD executes a contiguous run of the
    // triangular enumeration -> panel reuse in its private L2.
    const int b = ((blockIdx.x & 7) * (NBLK / 8)) + (blockIdx.x >> 3);

    const f16_t *Ap, *Bp;             // packed panel bases (panel 0)
    const float *nA, *nB;
    int tr, tc;
    double coef;
    if (b < 2 * TRI) {
        int u = (b < TRI) ? b : b - TRI;
        int r = 0;
        while (u >= NT - r) { u -= NT - r; r++; }
        tr = r; tc = r + u;
        double w = (tr == tc) ? 1.0 : 2.0;   // off-diagonal tiles count twice
        if (b < TRI) { Ap = Xp; Bp = Xp; nA = nx; nB = nx;
                       coef = w / ((double)NROWS * (double)(NROWS - 1)); }
        else         { Ap = Yp; Bp = Yp; nA = ny; nB = ny;
                       coef = w / ((double)MROWS * (double)(MROWS - 1)); }
    } else {
        int u = b - 2 * TRI;
        tr = u >> 5; tc = u & 31;
        Ap = Xp; Bp = Yp; nA = nx; nB = ny;
        coef = -2.0 / ((double)NROWS * (double)MROWS);
    }

    const int t    = threadIdx.x;
    const int wave = t >> 6;            // 0..3; waves 2x2: wm=wave>>1, wn=wave&1
    const int lane = t & 63;
    const int wm   = wave >> 1;
    const int wn   = wave & 1;

    // staging: 16 glds instrs (2 tiles x 8 row-groups of 16 rows); wave w
    // issues instrs w*4 .. w*4+3. Per instr: 64 lanes x 16 B = 16 rows x
    // 64 B -- CONTIGUOUS 1 KB in the packed panel (row stride = 64 B).
    // Lane l -> LDS slot (row lrow, chunk l&3) fixed by HW; lane fetches
    // global chunk (l&3)^f(lrow) so slot c' holds chunk c'^f(row).
    const int lrow = lane >> 2;         // 0..15 within row-group
    const int schunk = (lane & 3) ^ ((lrow ^ (lrow >> 2)) & 3);
    const f16_t* gsrc[4];
    int ldsoff[4];
    #pragma unroll
    for (int i = 0; i < 4; i++) {
        int idx = wave * 4 + i;         // 0..15
        int tile = idx >> 3;            // 0=A, 1=B
        int rg   = idx & 7;             // row-group
        const f16_t* base = tile ? (Bp + (size_t)tc * BM * BK)
                                 : (Ap + (size_t)tr * BM * BK);
        gsrc[i] = base + (size_t)(rg * 16 + lrow) * BK + schunk * 8;
        ldsoff[i] = tile * TILE + rg * 16 * BK;   // wave-uniform base
    }

    const int m    = lane & 15;         // row within 16x16 subtile
    const int quad = lane >> 4;         // k-chunk: k = quad*8 + j
    const int ac   = quad ^ ((m ^ (m >> 2)) & 3);  // swizzled read chunk

    // hoist epilogue norm loads off the critical tail
    float na[16], nb[4];
    #pragma unroll
    for (int i = 0; i < 4; i++) {
        #pragma unroll
        for (int r = 0; r < 4; r++)
            na[i * 4 + r] = nA[tr * BM + wm * 64 + i * 16 + quad * 4 + r];
        nb[i] = nB[tc * BM + wn * 64 + i * 16 + m];
    }

    floatx4 acc_r[4][4];
    #pragma unroll
    for (int i = 0; i < 4; i++)
        #pragma unroll
        for (int j = 0; j < 4; j++) acc_r[i][j] = (floatx4){0.f, 0.f, 0.f, 0.f};

    for (int kt = 0; kt < NKT; kt++) {
        const size_t ko = (size_t)kt * PSTRIDE;   // next packed K-panel
        __syncthreads();                 // previous compute done before overwrite
        #pragma unroll
        for (int i = 0; i < 4; i++) {
            __builtin_amdgcn_global_load_lds(
                (const __attribute__((address_space(1))) void*)(gsrc[i] + ko),
                (__attribute__((address_space(3))) void*)(lds + ldsoff[i]),
                16, 0, 0);
        }
        __syncthreads();                 // drains vmcnt before barrier

        f16x8 ah[4], bh[4];
        #pragma unroll
        for (int s = 0; s < 4; s++) {
            int arow = wm * 64 + s * 16 + m;
            int brow = wn * 64 + s * 16 + m;
            ah[s] = *(const f16x8*)&lds[arow * BK + ac * 8];
            bh[s] = *(const f16x8*)&lds[TILE + brow * BK + ac * 8];
        }
        #pragma unroll
        for (int i = 0; i < 4; i++)
            #pragma unroll
            for (int j = 0; j < 4; j++)
                acc_r[i][j] = __builtin_amdgcn_mfma_f32_16x16x32_f16(ah[i], bh[j], acc_r[i][j], 0, 0, 0);
    }

    // epilogue: C/D layout col=lane&15 (B-row), row=quad*4+reg (A-row)
    const float inv_s2 = 1.0f / 2025.0f;
    float lsum = 0.f;
    #pragma unroll
    for (int i = 0; i < 4; i++)
        #pragma unroll
        for (int j = 0; j < 4; j++)
            #pragma unroll
            for (int r = 0; r < 4; r++) {
                float arg = (2.f * acc_r[i][j][r] - na[i * 4 + r] - nb[j]) * inv_s2;
                lsum += __expf(arg);
            }

    // in-wave fp64 reduce (no barriers), then 4-wave LDS combine
    double d = (double)lsum;
    #pragma unroll
    for (int off = 32; off > 0; off >>= 1) d += __shfl_down(d, off);
    if (lane == 0) wred[wave] = d;
    __syncthreads();
    if (t == 0) {
        double part = (wred[0] + wred[1] + wred[2] + wred[3]) * coef;
        // fused final reduce: device-scope fp64 atomic, then count; the
        // vmcnt(0) orders this block's sum-add before its cnt-add, so the
        // block that sees cnt == NBLK-1 knows all sums are in.
        atomicAdd(gsum, part);
        asm volatile("s_waitcnt vmcnt(0)" ::: "memory");
        int old = atomicAdd(gcnt, 1);
        if (old == NBLK - 1) {
            double s = atomicAdd(gsum, 0.0);   // atomic read: coherent total
            // analytic diagonal subtraction: 1/(n-1) + 1/(m-1)
            out[0] = (float)(s - 1.0 / (double)(NROWS - 1)
                               - 1.0 / (double)(MROWS - 1));
        }
    }
}

extern "C" void kernel_launch(void* const* d_in, const int* in_sizes, int n_in,
                              void* d_out, int out_size, void* d_ws, size_t ws_size,
                              hipStream_t stream) {
    const float* X = (const float*)d_in[0];   // inputs  [4096,1024] fp32
    const float* Y = (const float*)d_in[1];   // samples [4096,1024] fp32
    float* out = (float*)d_out;

    // workspace: gsum|gcnt | nx | ny | Xp | Yp  (~16.7 MB)
    char* p = (char*)d_ws;
    double* gsum = (double*)p;
    int* gcnt = (int*)(p + sizeof(double));   p += 256;
    float* nx = (float*)p;                    p += (size_t)NROWS * sizeof(float);
    float* ny = (float*)p;                    p += (size_t)MROWS * sizeof(float);
    f16_t* Xp = (f16_t*)p;                    p += (size_t)NROWS * DDIM * sizeof(f16_t);
    f16_t* Yp = (f16_t*)p;

    convert_kernel<<<(NROWS + MROWS) / 4, 256, 0, stream>>>(X, Y, Xp, Yp, nx, ny, gsum, gcnt);
    mmd_mfma<<<NBLK, 256, 0, stream>>>(Xp, Yp, nx, ny, gsum, gcnt, out);
}

// Round 7
// 156.095 us; speedup vs baseline: 2.0888x; 1.1539x over previous
//
#include <hip/hip_runtime.h>
#include <math.h>

// MMD loss, fp16 MFMA. N=M=4096, D=1024, sigma^2=2025.
// Round 17: CLEAN A/B vs R0. R6 post-mortem: bundled T1 + atomic-fuse +
// packing regressed; unbundled via counters -- packing was the good part
// (FETCH 128->89MB), and SQ_LDS_BANK_CONFLICT=8519680 (=4096cy/block
// EXACTLY, 12-14% of CU cycles) proved R0's old read-swizzle was never
// conflict-free, while the R1-5 pattern measured a true 0. This round =
// R0's proven TLP structure (128x128, 4 waves, 2-barrier drain loop,
// ~2+ blocks/CU, 3 launches, fp64 partials) with exactly two deltas:
//  (a) packed K-major panels Xp/Yp[kt][row][32]: every glds reads 1KB
//      contiguous (16 rows x 64B at row-stride 64B);
//  (b) the MEASURED-0-conflict LDS pattern from R1-5: split ldsA/ldsB,
//      f(r) = ((r>>1)&3) on both store-fetch and read sides.
// No T1 (working set is L3-fit: documented ~-2%), no device atomics.

typedef _Float16 f16_t;
typedef _Float16 f16x4 __attribute__((ext_vector_type(4)));
typedef _Float16 f16x8 __attribute__((ext_vector_type(8)));
typedef float floatx4 __attribute__((ext_vector_type(4)));

#define NROWS 4096
#define MROWS 4096
#define DDIM  1024
#define BM    128
#define BK    32                      // fp16 elements per K-step (64 B/row)
#define TILE  (BM * BK)               // 4096 f16 per tile (8 KB)
#define NKT   (DDIM / BK)             // 32 K-steps
#define PSTRIDE (4096 * BK)           // f16 elems per packed K-panel (256 KB)
#define NT    (NROWS / BM)            // 32 tiles per dim
#define TRI   (NT * (NT + 1) / 2)     // 528 triangular tiles
#define NBLK  (2 * TRI + NT * NT)     // 2080 blocks

// ---------------------------------------------------------------- convert
// Wave-per-row: 2048 blocks x 4 waves cover 8192 rows. Each lane loads
// 4 float4 (fully coalesced), converts to fp16, stores to the PACKED layout
// Xp[kt][row][32]: lane l, iter c covers k = c*256+l*4 -> panel c*8+(l>>3),
// pos (l&7)*4. Norm of the ROUNDED row shuffle-reduced in-wave.
__global__ __launch_bounds__(256) void convert_kernel(
    const float* __restrict__ X, const float* __restrict__ Y,
    f16_t* __restrict__ Xp, f16_t* __restrict__ Yp,
    float* __restrict__ nx, float* __restrict__ ny) {
    const int wid  = threadIdx.x >> 6;
    const int lane = threadIdx.x & 63;
    const int row  = blockIdx.x * 4 + wid;        // 0..8191
    const float* src;
    f16_t* dstp;
    float* nrm;
    int r;
    if (row < NROWS) {
        r = row;         src = X + (size_t)r * DDIM;
        dstp = Xp;  nrm = nx;
    } else {
        r = row - NROWS; src = Y + (size_t)r * DDIM;
        dstp = Yp;  nrm = ny;
    }
    const float4* s4 = (const float4*)src;        // 256 float4 per row
    float s = 0.f;
    #pragma unroll
    for (int c = 0; c < 4; c++) {
        float4 v = s4[c * 64 + lane];
        f16x4 h;
        h[0] = (f16_t)v.x; h[1] = (f16_t)v.y;
        h[2] = (f16_t)v.z; h[3] = (f16_t)v.w;
        // k = c*256 + lane*4 -> kt = c*8 + (lane>>3), pos = (lane&7)*4
        *(f16x4*)(dstp + (size_t)(c * 8 + (lane >> 3)) * PSTRIDE
                       + (size_t)r * BK + (lane & 7) * 4) = h;
        float h0 = (float)h[0], h1 = (float)h[1];
        float h2 = (float)h[2], h3 = (float)h[3];
        s += h0 * h0 + h1 * h1 + h2 * h2 + h3 * h3;
    }
    #pragma unroll
    for (int off = 32; off > 0; off >>= 1) s += __shfl_down(s, off);
    if (lane == 0) nrm[r] = s;
}

// ---------------------------------------------------------------- main GEMM
__global__ __launch_bounds__(256) void mmd_mfma(
    const f16_t* __restrict__ Xp, const f16_t* __restrict__ Yp,
    const float* __restrict__ nx, const float* __restrict__ ny,
    double* __restrict__ partials) {
    // Split A/B tiles, each BM x BK fp16 = 8 KB. Row r of a tile stores
    // logical chunk c (16 B) at phys chunk c ^ ((r>>1)&3) -- the R1-5
    // pattern, MEASURED 0 bank conflicts.
    __shared__ __align__(16) f16_t ldsA[TILE];
    __shared__ __align__(16) f16_t ldsB[TILE];
    __shared__ double wred[4];

    const int b = blockIdx.x;
    const f16_t *Ap, *Bp;             // packed panel bases (panel 0)
    const float *nA, *nB;
    int tr, tc;
    double coef;
    if (b < 2 * TRI) {
        int u = (b < TRI) ? b : b - TRI;
        int r = 0;
        while (u >= NT - r) { u -= NT - r; r++; }
        tr = r; tc = r + u;
        double w = (tr == tc) ? 1.0 : 2.0;   // off-diagonal tiles count twice
        if (b < TRI) { Ap = Xp; Bp = Xp; nA = nx; nB = nx;
                       coef = w / ((double)NROWS * (double)(NROWS - 1)); }
        else         { Ap = Yp; Bp = Yp; nA = ny; nB = ny;
                       coef = w / ((double)MROWS * (double)(MROWS - 1)); }
    } else {
        int u = b - 2 * TRI;
        tr = u >> 5; tc = u & 31;
        Ap = Xp; Bp = Yp; nA = nx; nB = ny;
        coef = -2.0 / ((double)NROWS * (double)MROWS);
    }

    const int t    = threadIdx.x;
    const int wave = t >> 6;            // 0..3; waves 2x2: wm=wave>>1, wn=wave&1
    const int lane = t & 63;
    const int wm   = wave >> 1;
    const int wn   = wave & 1;

    // staging: 16 glds instrs (2 tiles x 8 row-groups of 16 rows); wave w
    // issues instrs w*4 .. w*4+3. Per instr: 64 lanes x 16 B = 16 rows x
    // 64 B -- CONTIGUOUS 1 KB in the packed panel (row stride = 64 B).
    // glds writes linearly: lane l -> row lr=l>>2, phys chunk l&3; lane
    // fetches global chunk (l&3)^((lr>>1)&3) = (l&3)^((l>>3)&3) so phys
    // chunk p of row r holds logical p^((r>>1)&3).
    const int lr = lane >> 2;           // 0..15 within row-group
    const int lc = (lane & 3) ^ ((lane >> 3) & 3);
    const f16_t* gsrc[4];
    f16_t* ldst[4];
    #pragma unroll
    for (int i = 0; i < 4; i++) {
        int idx = wave * 4 + i;         // 0..15
        int tile = idx >> 3;            // 0=A, 1=B
        int rg   = idx & 7;             // row-group
        const f16_t* base = tile ? (Bp + (size_t)tc * BM * BK)
                                 : (Ap + (size_t)tr * BM * BK);
        gsrc[i] = base + (size_t)(rg * 16 + lr) * BK + lc * 8;
        ldst[i] = (tile ? ldsB : ldsA) + rg * 16 * BK;   // wave-uniform base
    }

    const int m    = lane & 15;         // row within 16x16 subtile
    const int quad = lane >> 4;         // k-chunk: k = quad*8 + j
    // read-side swizzled chunk offset: phys = quad ^ ((row>>1)&3); rows are
    // s*16 + m (16|s*16) so f depends only on m.
    const int sw8  = (quad ^ ((m >> 1) & 3)) * 8;

    // hoist epilogue norm loads off the critical tail
    float na[16], nb[4];
    #pragma unroll
    for (int i = 0; i < 4; i++) {
        #pragma unroll
        for (int r = 0; r < 4; r++)
            na[i * 4 + r] = nA[tr * BM + wm * 64 + i * 16 + quad * 4 + r];
        nb[i] = nB[tc * BM + wn * 64 + i * 16 + m];
    }

    floatx4 acc_r[4][4];
    #pragma unroll
    for (int i = 0; i < 4; i++)
        #pragma unroll
        for (int j = 0; j < 4; j++) acc_r[i][j] = (floatx4){0.f, 0.f, 0.f, 0.f};

    for (int kt = 0; kt < NKT; kt++) {
        const size_t ko = (size_t)kt * PSTRIDE;   // next packed K-panel
        __syncthreads();                 // previous compute done before overwrite
        #pragma unroll
        for (int i = 0; i < 4; i++) {
            __builtin_amdgcn_global_load_lds(
                (const __attribute__((address_space(1))) void*)(gsrc[i] + ko),
                (__attribute__((address_space(3))) void*)ldst[i],
                16, 0, 0);
        }
        __syncthreads();                 // drains vmcnt before barrier

        f16x8 ah[4], bh[4];
        #pragma unroll
        for (int s = 0; s < 4; s++) {
            ah[s] = *(const f16x8*)&ldsA[(wm * 64 + s * 16 + m) * BK + sw8];
            bh[s] = *(const f16x8*)&ldsB[(wn * 64 + s * 16 + m) * BK + sw8];
        }
        #pragma unroll
        for (int i = 0; i < 4; i++)
            #pragma unroll
            for (int j = 0; j < 4; j++)
                acc_r[i][j] = __builtin_amdgcn_mfma_f32_16x16x32_f16(ah[i], bh[j], acc_r[i][j], 0, 0, 0);
    }

    // epilogue: C/D layout col=lane&15 (B-row), row=quad*4+reg (A-row)
    const float inv_s2 = 1.0f / 2025.0f;
    float lsum = 0.f;
    #pragma unroll
    for (int i = 0; i < 4; i++)
        #pragma unroll
        for (int j = 0; j < 4; j++)
            #pragma unroll
            for (int r = 0; r < 4; r++) {
                float arg = (2.f * acc_r[i][j][r] - na[i * 4 + r] - nb[j]) * inv_s2;
                lsum += __expf(arg);
            }

    // in-wave fp64 reduce (no barriers), then 4-wave LDS combine; plain store
    double d = (double)lsum;
    #pragma unroll
    for (int off = 32; off > 0; off >>= 1) d += __shfl_down(d, off);
    if (lane == 0) wred[wave] = d;
    __syncthreads();
    if (t == 0)
        partials[b] = (wred[0] + wred[1] + wred[2] + wred[3]) * coef;
}

__global__ __launch_bounds__(256) void final_reduce(const double* __restrict__ partials,
                                                    float* __restrict__ out) {
    __shared__ double red[256];
    int t = threadIdx.x;
    double s = 0.0;
    for (int i = t; i < NBLK; i += 256) s += partials[i];
    red[t] = s;
    __syncthreads();
    for (int off = 128; off > 0; off >>= 1) {
        if (t < off) red[t] += red[t + off];
        __syncthreads();
    }
    if (t == 0) {
        // analytic diagonal subtraction: 1/(n-1) + 1/(m-1)
        double mmd = red[0] - 1.0 / (double)(NROWS - 1) - 1.0 / (double)(MROWS - 1);
        out[0] = (float)mmd;
    }
}

extern "C" void kernel_launch(void* const* d_in, const int* in_sizes, int n_in,
                              void* d_out, int out_size, void* d_ws, size_t ws_size,
                              hipStream_t stream) {
    const float* X = (const float*)d_in[0];   // inputs  [4096,1024] fp32
    const float* Y = (const float*)d_in[1];   // samples [4096,1024] fp32
    float* out = (float*)d_out;

    // workspace: partials | nx | ny | Xp | Yp  (~16.7 MB)
    char* p = (char*)d_ws;
    double* partials = (double*)p;            p += ((size_t)NBLK * sizeof(double) + 255) & ~255ULL;
    float* nx = (float*)p;                    p += (size_t)NROWS * sizeof(float);
    float* ny = (float*)p;                    p += (size_t)MROWS * sizeof(float);
    f16_t* Xp = (f16_t*)p;                    p += (size_t)NROWS * DDIM * sizeof(f16_t);
    f16_t* Yp = (f16_t*)p;

    convert_kernel<<<(NROWS + MROWS) / 4, 256, 0, stream>>>(X, Y, Xp, Yp, nx, ny);
    mmd_mfma<<<NBLK, 256, 0, stream>>>(Xp, Yp, nx, ny, partials);
    final_reduce<<<1, 256, 0, stream>>>(partials, out);
}